// Round 8
// baseline (239.826 us; speedup 1.0000x reference)
//
#include <hip/hip_runtime.h>
#include <stdint.h>

// Problem constants
#define B_SZ   8192
#define IN_DIM 320      // S + A
#define H_DIM  1024
#define E_NUM  8
#define OUT_DIM 257     // S + 1
#define MAXT1  72       // TM=128 tile table (8192/128 + 8 experts)
#define MAXT2  136      // TM=64 tile table  (8192/64 + 8 experts)

typedef __bf16 bf16x8 __attribute__((ext_vector_type(8)));
typedef float  f32x4  __attribute__((ext_vector_type(4)));

typedef unsigned int __attribute__((address_space(1))) as1_uint;
typedef unsigned int __attribute__((address_space(3))) as3_uint;

__device__ __forceinline__ void gload_lds16(const void* g, void* l) {
    // async global->LDS, 16B/lane; LDS dest is wave-uniform base + lane*16
    __builtin_amdgcn_global_load_lds((const as1_uint*)g, (as3_uint*)l, 16, 0, 0);
}

__device__ __forceinline__ unsigned short f2bf(float f) {
    unsigned int u = __float_as_uint(f);
    return (unsigned short)((u + 0x7fffu + ((u >> 16) & 1u)) >> 16);  // RNE
}

// ---------------------------------------------------------------------------
// Transpose-convert nkt 64x64 tiles (verified R1 body): float4 global loads
// -> bf16 -> padded LDS (stride 65, <=2-way banks) -> ushort4 global stores.
// (E,K,Nsrc) f32 src -> (E,dstRows,K) bf16 dst, tile (kt,nt), column n0=nt*64.
__device__ __forceinline__ void transpose_tiles(
    char* smem, int e, int nt, int kt0, int nkt,
    int K, int Nsrc, int dstRows, bool vec,
    const float* __restrict__ src, unsigned short* __restrict__ dst) {
    unsigned short (*tileU)[65] = (unsigned short(*)[65])smem;
    int tid = threadIdx.x;
    const float* s = src + (size_t)e * K * Nsrc;
    unsigned short* d = dst + (size_t)e * dstRows * K;
    int c4 = (tid & 15) * 4;      // 4 consecutive cols per thread
    int rb = tid >> 4;            // 16 rows per pass
    int n0 = nt * 64;
    for (int kt = kt0; kt < kt0 + nkt; kt++) {
        int k0 = kt * 64;
#pragma unroll
        for (int p = 0; p < 4; p++) {
            int r = rb + p * 16;
            const float* sp = s + (size_t)(k0 + r) * Nsrc + n0 + c4;
            float4 v;
            if (vec) v = *(const float4*)sp;
            else { v.x = sp[0]; v.y = sp[1]; v.z = sp[2]; v.w = sp[3]; }
            tileU[r][c4 + 0] = f2bf(v.x);
            tileU[r][c4 + 1] = f2bf(v.y);
            tileU[r][c4 + 2] = f2bf(v.z);
            tileU[r][c4 + 3] = f2bf(v.w);
        }
        __syncthreads();
#pragma unroll
        for (int p = 0; p < 4; p++) {
            int n = rb + p * 16;
            ushort4 o;
            o.x = tileU[c4 + 0][n];
            o.y = tileU[c4 + 1][n];
            o.z = tileU[c4 + 2][n];
            o.w = tileU[c4 + 3][n];
            *(ushort4*)&d[(size_t)(n0 + n) * K + k0 + c4] = o;
        }
        __syncthreads();             // tileU reused next kt
    }
}

// ---------------------------------------------------------------------------
// Bucket rows by expert + build BOTH tile tables (verified R5/R6 body).
__device__ __forceinline__ void prep_bucket(
    char* smem, const int* __restrict__ idx, int* __restrict__ order,
    int* __restrict__ te1, int* __restrict__ tp1, int* __restrict__ tc1,
    int* __restrict__ te2, int* __restrict__ tp2, int* __restrict__ tc2) {
    int (*scnt)[E_NUM] = (int(*)[E_NUM])smem;
    int tid = threadIdx.x;
    int shard = tid & 15;
    if (tid < 128) ((int*)scnt)[tid] = 0;
    __syncthreads();
    for (int b = tid; b < B_SZ; b += 256) atomicAdd(&scnt[shard][idx[b]], 1);
    __syncthreads();
    if (tid == 0) {
        int pos = 0, t1 = 0, t2 = 0;
        for (int e = 0; e < E_NUM; e++) {
            int start = pos;
            for (int s = 0; s < 16; s++) { int c = scnt[s][e]; scnt[s][e] = pos; pos += c; }
            int tot = pos - start;
            for (int st = 0; st < tot; st += 128) {
                te1[t1] = e; tp1[t1] = start + st; tc1[t1] = min(128, tot - st); t1++;
            }
            for (int st = 0; st < tot; st += 64) {
                te2[t2] = e; tp2[t2] = start + st; tc2[t2] = min(64, tot - st); t2++;
            }
        }
        for (; t1 < MAXT1; t1++) { te1[t1] = 0; tp1[t1] = 0; tc1[t1] = 0; }
        for (; t2 < MAXT2; t2++) { te2[t2] = 0; tp2[t2] = 0; tc2[t2] = 0; }
    }
    __syncthreads();
    for (int b = tid; b < B_SZ; b += 256) {
        int e = idx[b];
        int p = atomicAdd(&scnt[shard][e], 1);
        order[p] = b;
    }
}

// ---------------------------------------------------------------------------
// Dispatch 1: bucket (bid 0) | x-concat (bid 1..320, 8 items each) |
// W1 transpose (bid 321..960, one 64x64 tile each).
__global__ __launch_bounds__(256)
void k_prepA(const float* __restrict__ state, const float* __restrict__ action,
             const int* __restrict__ idx, const float* __restrict__ W1,
             unsigned short* __restrict__ xb, unsigned short* __restrict__ w1t,
             int* __restrict__ order,
             int* __restrict__ te1, int* __restrict__ tp1, int* __restrict__ tc1,
             int* __restrict__ te2, int* __restrict__ tp2, int* __restrict__ tc2) {
    __shared__ __align__(16) char smem[8448];
    int bid = blockIdx.x, tid = threadIdx.x;

    if (bid == 0) {
        prep_bucket(smem, idx, order, te1, tp1, tc1, te2, tp2, tc2);
        return;
    }
    if (bid <= 320) {
#pragma unroll
        for (int k = 0; k < 8; k++) {
            int q = ((bid - 1) * 8 + k) * 256 + tid;   // quad id: b*80 + j
            int b = q / 80, j = q % 80;
            float4 v = (j < 64) ? ((const float4*)state)[b * 64 + j]
                                : ((const float4*)action)[b * 16 + (j - 64)];
            ushort4 o;
            o.x = f2bf(v.x); o.y = f2bf(v.y); o.z = f2bf(v.z); o.w = f2bf(v.w);
            ((ushort4*)xb)[q] = o;
        }
        return;
    }
    // W1: (8,320,1024) -> (8,1024,320); 640 tiles, 1 per block
    int r = bid - 321;                   // 0..639
    int e = r / 80, m = r % 80;
    transpose_tiles(smem, e, m % 16, m / 16, 1, IN_DIM, H_DIM, H_DIM, true, W1, w1t);
}

// ---------------------------------------------------------------------------
// Grouped-GEMM tile (R4-verified body). TMxTN, 2-stage LDS dbuf, 4 waves in a
// 2x2 grid — wave (wm,wn) computes a (TM/2)x(TN/2) quadrant. LDS XOR-swizzle:
// slot (row, chunk c) holds global 16B chunk c ^ ((row>>1)&3) — 0 measured
// bank conflicts. Wt: (E, wtRows, K) bf16, N-major.
// MODE 0: Hout[(p0+m)*1024 + n] = bf16(relu(acc + bias))
// MODE 1 (layer 3 + fused reward): n<256 -> Out[row*256+n] = state + acc + b;
//         n==256 -> Out[B*256 + row] = acc + b;  n>256 -> discard.
template <int K, int TM, int TN, bool GATHER, int MODE>
__device__ __forceinline__ void gemm_tile(
    char* lds, int t, int ny,
    const unsigned short* __restrict__ Abase,
    const unsigned short* __restrict__ Wt, int wtRows,
    const float* __restrict__ bias, int bstride,
    unsigned short* __restrict__ Hout,
    float* __restrict__ Out, const float* __restrict__ state,
    const int* __restrict__ order,
    const int* __restrict__ te, const int* __restrict__ tp0,
    const int* __restrict__ tcnt) {
    constexpr int NI  = K / 32;
    constexpr int WM  = TM / 2, MF = WM / 16;
    constexpr int WN  = TN / 2, NF = WN / 16;
    constexpr int ABY = TM * 64;          // A stage bytes (TM rows x 64B)
    constexpr int BBY = TN * 64;          // B stage bytes
    constexpr int STG = ABY + BBY;

    int cnt = tcnt[t];
    if (cnt == 0) return;
    int e = te[t], p0 = tp0[t];
    int n0 = ny * TN;
    int tid = threadIdx.x;
    int w = tid >> 6, lane = tid & 63;
    int wm = w >> 1, wn = w & 1;          // 2x2 wave grid

    int r0 = tid >> 2;
    int cg2 = (tid & 3) ^ ((r0 >> 1) & 3);
    int rc0 = r0 < cnt ? r0 : cnt - 1;              // clamp; masked in epilogue
    long a0 = GATHER ? order[p0 + rc0] : (p0 + rc0);
    const unsigned short* aP0 = Abase + (size_t)a0 * K + cg2 * 8;
    const unsigned short* aP1 = aP0;
    if (TM == 128) {
        int rc1 = (r0 + 64) < cnt ? (r0 + 64) : cnt - 1;
        long a1 = GATHER ? order[p0 + rc1] : (p0 + rc1);
        aP1 = Abase + (size_t)a1 * K + cg2 * 8;
    }
    const unsigned short* bP0 = Wt + ((size_t)e * wtRows + n0 + r0) * K + cg2 * 8;
    const unsigned short* bP1 = bP0 + (size_t)64 * K;

    auto stage = [&](int k0s, int sb) {
        gload_lds16(aP0 + k0s, lds + sb + tid * 16);
        if (TM == 128)
            gload_lds16(aP1 + k0s, lds + sb + 4096 + tid * 16);
        gload_lds16(bP0 + k0s, lds + sb + ABY + tid * 16);
        if (TN == 128)
            gload_lds16(bP1 + k0s, lds + sb + ABY + 4096 + tid * 16);
    };

    f32x4 acc[MF][NF];
#pragma unroll
    for (int i = 0; i < MF; i++)
#pragma unroll
        for (int j = 0; j < NF; j++) acc[i][j] = (f32x4)0.f;

    const int fm   = lane & 15;
    const int kc   = lane >> 4;
    const int koff = ((kc ^ ((fm >> 1) & 3)) * 8);  // swizzled k-chunk offset

    stage(0, 0);
    for (int it = 0; it < NI; ++it) {
        __syncthreads();                 // drains tile-it loads (issued 1 iter ago)
        if (it + 1 < NI) stage((it + 1) * 32, ((it + 1) & 1) * STG);
        const unsigned short* Ls = (const unsigned short*)(lds + (it & 1) * STG);
        const unsigned short* As = Ls + wm * WM * 32;           // wave's WM-row A half
        const unsigned short* Bs = Ls + ABY / 2 + wn * WN * 32; // wave's WN-col B slice

        bf16x8 af[MF], bf[NF];
#pragma unroll
        for (int i = 0; i < MF; i++)
            af[i] = *(const bf16x8*)&As[(i * 16 + fm) * 32 + koff];
#pragma unroll
        for (int j = 0; j < NF; j++)
            bf[j] = *(const bf16x8*)&Bs[(j * 16 + fm) * 32 + koff];
#pragma unroll
        for (int i = 0; i < MF; i++)
#pragma unroll
            for (int j = 0; j < NF; j++)
                acc[i][j] = __builtin_amdgcn_mfma_f32_16x16x32_bf16(
                    af[i], bf[j], acc[i][j], 0, 0, 0);
    }

    // epilogue: C/D mapping col = lane&15, row = (lane>>4)*4 + reg
    int col = lane & 15, rq = lane >> 4;
#pragma unroll
    for (int j = 0; j < NF; j++) {
        int n = n0 + wn * WN + j * 16 + col;
        float bv = (MODE == 0) ? bias[e * bstride + n]
                               : ((n <= 256) ? bias[e * bstride + n] : 0.f);
#pragma unroll
        for (int i = 0; i < MF; i++) {
#pragma unroll
            for (int rr = 0; rr < 4; rr++) {
                int m = wm * WM + i * 16 + rq * 4 + rr;
                if (m < cnt) {
                    float v = acc[i][j][rr] + bv;
                    if (MODE == 0) {
                        Hout[(size_t)(p0 + m) * H_DIM + n] = f2bf(fmaxf(v, 0.f));
                    } else {
                        int row = order[p0 + m];
                        if (n < 256) {
                            size_t o = (size_t)row * 256 + n;
                            Out[o] = state[o] + v;
                        } else if (n == 256) {
                            Out[(size_t)B_SZ * 256 + row] = v;   // reward
                        }
                    }
                }
            }
        }
    }
}

// ---------------------------------------------------------------------------
// GEMM dispatch with co-scheduled transpose blocks (bid >= GBLK):
// EXTRA 0: none. EXTRA 1: W2 transpose (512 blocks x 4 kt-tiles, R6 mapping).
// EXTRA 2: W3 transpose (32 blocks x 16 kt-tiles) + reward column (32 blocks).
// The extra blocks backfill the 2-3 idle slots/CU the GEMM leaves (5 blocks/CU
// fit at 32KB LDS) and their output is consumed one dispatch later.
template <int K, int TM, int TN, bool GATHER, int MODE, int EXTRA, int GBLK, int TT>
__global__ __launch_bounds__(256, 2)
void k_gemm(const unsigned short* __restrict__ Abase,
            const unsigned short* __restrict__ Wt, int wtRows,
            const float* __restrict__ bias, int bstride,
            unsigned short* __restrict__ Hout,
            float* __restrict__ Out, const float* __restrict__ state,
            const int* __restrict__ order,
            const int* __restrict__ te, const int* __restrict__ tp0,
            const int* __restrict__ tcnt,
            const float* __restrict__ Wsrc, unsigned short* __restrict__ Wdst) {
    constexpr int STG = TM * 64 + TN * 64;
    __shared__ __align__(16) char lds[2 * STG];
    int bid = blockIdx.x;

    if (EXTRA != 0 && bid >= GBLK) {
        if constexpr (EXTRA == 1) {
            int b = bid - GBLK;          // 0..511: W2 (8,1024,1024)->(8,1024,1024)
            int e = b >> 6, r = b & 63;
            transpose_tiles(lds, e, r >> 2, (r & 3) * 4, 4,
                            H_DIM, H_DIM, H_DIM, true, Wsrc, Wdst);
        } else if constexpr (EXTRA == 2) {
            int b = bid - GBLK;          // 0..63
            if (b < 32) {                // W3 (8,1024,257)->rows 0..255 of (8,320,1024)
                transpose_tiles(lds, b >> 2, b & 3, 0, 16,
                                H_DIM, OUT_DIM, 320, false, Wsrc, Wdst);
            } else {                     // W3 reward column -> w3t row 256
                int i = (b - 32) * 256 + threadIdx.x;   // 8192 = 8e x 1024k
                int e = i >> 10, k = i & 1023;
                Wdst[((size_t)e * 320 + 256) * H_DIM + k] =
                    f2bf(Wsrc[((size_t)e * H_DIM + k) * OUT_DIM + 256]);
            }
        }
        return;
    }
    gemm_tile<K, TM, TN, GATHER, MODE>(lds, bid % TT, bid / TT,
        Abase, Wt, wtRows, bias, bstride, Hout, Out, state,
        order, te, tp0, tcnt);
}

// ---------------------------------------------------------------------------
extern "C" void kernel_launch(void* const* d_in, const int* in_sizes, int n_in,
                              void* d_out, int out_size, void* d_ws, size_t ws_size,
                              hipStream_t stream) {
    const float* state  = (const float*)d_in[0];
    const float* action = (const float*)d_in[1];
    const int*   idx    = (const int*)d_in[2];
    const float* W1     = (const float*)d_in[3];
    const float* b1     = (const float*)d_in[4];
    const float* W2     = (const float*)d_in[5];
    const float* b2     = (const float*)d_in[6];
    const float* W3     = (const float*)d_in[7];
    const float* b3     = (const float*)d_in[8];
    float* out = (float*)d_out;

    char* ws = (char*)d_ws;
    size_t off = 0;
    auto alloc = [&](size_t bytes) -> void* {
        void* p = ws + off;
        off = (off + bytes + 255) & ~(size_t)255;
        return p;
    };
    unsigned short* xb  = (unsigned short*)alloc((size_t)B_SZ * IN_DIM * 2);
    unsigned short* w1t = (unsigned short*)alloc((size_t)E_NUM * H_DIM * IN_DIM * 2);
    unsigned short* w2t = (unsigned short*)alloc((size_t)E_NUM * H_DIM * H_DIM * 2);
    unsigned short* w3t = (unsigned short*)alloc((size_t)E_NUM * 320 * H_DIM * 2);
    unsigned short* h1  = (unsigned short*)alloc((size_t)B_SZ * H_DIM * 2);
    unsigned short* h2  = (unsigned short*)alloc((size_t)B_SZ * H_DIM * 2);
    int* order = (int*)alloc(B_SZ * 4);
    int* te1   = (int*)alloc(MAXT1 * 4);
    int* tp1   = (int*)alloc(MAXT1 * 4);
    int* tc1   = (int*)alloc(MAXT1 * 4);
    int* te2   = (int*)alloc(MAXT2 * 4);
    int* tp2   = (int*)alloc(MAXT2 * 4);
    int* tc2   = (int*)alloc(MAXT2 * 4);

    // dispatch 1: bucket + x-concat + W1 transpose  (961 blocks)
    k_prepA<<<961, 256, 0, stream>>>(state, action, idx, W1, xb, w1t, order,
                                     te1, tp1, tc1, te2, tp2, tc2);

    // dispatch 2: layer-1 GEMM (576 blocks) + W2 transpose (512 blocks)
    k_gemm<IN_DIM, 128, 128, true, 0, 1, 576, MAXT1>
        <<<1088, 256, 0, stream>>>(
        xb, w1t, H_DIM, b1, H_DIM, h1, nullptr, nullptr,
        order, te1, tp1, tc1, W2, w2t);

    // dispatch 3: layer-2 GEMM (576 blocks) + W3 transpose + reward (64 blocks)
    k_gemm<H_DIM, 128, 128, false, 0, 2, 576, MAXT1>
        <<<640, 256, 0, stream>>>(
        h1, w2t, H_DIM, b2, H_DIM, h2, nullptr, nullptr,
        order, te1, tp1, tc1, W3, w3t);

    // dispatch 4: layer-3 GEMM + fused reward write (680 blocks, 64x64 tiles)
    k_gemm<H_DIM, 64, 64, false, 1, 0, 680, MAXT2>
        <<<680, 256, 0, stream>>>(
        h2, w3t, 320, b3, OUT_DIM, nullptr, out, state,
        order, te2, tp2, tc2, nullptr, nullptr);
}